// Round 1
// baseline (1644.586 us; speedup 1.0000x reference)
//
#include <hip/hip_runtime.h>

// RGCN encoder: N=20000 nodes, E=640000 edges, F=64, H=128, L=2 layers,
// D=3 edge-attr dims, R=8 relations, block-diag B=4 blocks of c=32.
// h grows by concat: 20000 -> 60000 -> 180000 rows.

constexpr int H  = 128;
constexpr int F  = 64;
constexpr int D  = 3;
constexpr int R  = 8;
constexpr int B  = 4;
constexpr int C  = 32;
constexpr int ROWS = 8;
constexpr int SCAN_CHUNK = 512;

// ---------------- CSR build ----------------

__global__ void count_edges(const int* __restrict__ ei, const int* __restrict__ attr,
                            int* __restrict__ cnt, int E, int N) {
  int e = blockIdx.x * 256 + threadIdx.x;
  if (e >= E) return;
  int dst = ei[E + e];
  #pragma unroll
  for (int j = 0; j < D; ++j) {
    int r = attr[e * D + j];
    atomicAdd(&cnt[(j * R + r) * N + dst], 1);
  }
}

__global__ void scan_a(const int* __restrict__ cnt, int* __restrict__ cexcl,
                       int* __restrict__ bsum, int nseg) {
  __shared__ int tmp[2][SCAN_CHUNK];
  int t = threadIdx.x;
  int gid = blockIdx.x * SCAN_CHUNK + t;
  int v = (gid < nseg) ? cnt[gid] : 0;
  int pa = 0;
  tmp[0][t] = v;
  __syncthreads();
  for (int off = 1; off < SCAN_CHUNK; off <<= 1) {
    tmp[1 - pa][t] = tmp[pa][t] + ((t >= off) ? tmp[pa][t - off] : 0);
    pa = 1 - pa;
    __syncthreads();
  }
  int incl = tmp[pa][t];
  if (gid < nseg) cexcl[gid] = incl - v;
  if (t == SCAN_CHUNK - 1) bsum[blockIdx.x] = incl;
}

__global__ void scan_b(int* __restrict__ bsum, int nblk) {
  __shared__ int tmp[2][1024];
  int t = threadIdx.x;
  int v = (t < nblk) ? bsum[t] : 0;
  int pa = 0;
  tmp[0][t] = v;
  __syncthreads();
  for (int off = 1; off < 1024; off <<= 1) {
    tmp[1 - pa][t] = tmp[pa][t] + ((t >= off) ? tmp[pa][t - off] : 0);
    pa = 1 - pa;
    __syncthreads();
  }
  if (t < nblk) bsum[t] = tmp[pa][t] - v;  // exclusive
}

__global__ void scan_c(const int* __restrict__ cexcl, const int* __restrict__ bsum,
                       int* __restrict__ offs, int nseg, int total) {
  int gid = blockIdx.x * 256 + threadIdx.x;
  if (gid < nseg) offs[gid] = cexcl[gid] + bsum[gid / SCAN_CHUNK];
  if (gid == 0) offs[nseg] = total;
}

__global__ void copy_int(const int* __restrict__ a, int* __restrict__ b, int n) {
  int i = blockIdx.x * 256 + threadIdx.x;
  if (i < n) b[i] = a[i];
}

__global__ void fill_edges(const int* __restrict__ ei, const int* __restrict__ attr,
                           int* __restrict__ cursor, int* __restrict__ elist, int E, int N) {
  int e = blockIdx.x * 256 + threadIdx.x;
  if (e >= E) return;
  int src = ei[e];
  int dst = ei[E + e];
  #pragma unroll
  for (int j = 0; j < D; ++j) {
    int r = attr[e * D + j];
    int p = atomicAdd(&cursor[(j * R + r) * N + dst], 1);
    elist[p] = src;  // store src id directly
  }
}

// ---------------- h0 = x @ emb ----------------

__global__ __launch_bounds__(128) void gemm_h0(const float* __restrict__ x,
                                               const float* __restrict__ emb,
                                               float* __restrict__ h0, int N) {
  __shared__ float xs[ROWS][F];
  int r0 = blockIdx.x * ROWS;
  for (int i = threadIdx.x; i < ROWS * F; i += 128)
    xs[i >> 6][i & 63] = x[(size_t)r0 * F + i];
  __syncthreads();
  int d = threadIdx.x;
  float acc[ROWS] = {};
  for (int k = 0; k < F; ++k) {
    float ev = emb[k * H + d];
    #pragma unroll
    for (int r = 0; r < ROWS; ++r) acc[r] = fmaf(xs[r][k], ev, acc[r]);
  }
  #pragma unroll
  for (int r = 0; r < ROWS; ++r) h0[(size_t)(r0 + r) * H + d] = acc[r];
}

// ---------------- fused RGCN conv layer ----------------
// out[j*N_all + n] = relu( sum_r (1/cnt) * blockdiag(W_r) @ (sum_{e in seg(r,n)} hsrc[src_e])
//                          + h[n] @ root_j + bias_j )

__global__ __launch_bounds__(128) void conv_kernel(
    const float* __restrict__ h, const float* __restrict__ hsrc,
    const int* __restrict__ offs, const int* __restrict__ elist,
    const float* __restrict__ Wall, const float* __restrict__ rootall,
    const float* __restrict__ biasall, float* __restrict__ out,
    int N_all, int NSRC) {
  const int j = blockIdx.y;
  const int row0 = blockIdx.x * ROWS;
  const int d = threadIdx.x;
  const int b = d >> 5, dd = d & 31;
  const float* W = Wall + (size_t)j * R * B * C * C;
  const float* root = rootall + (size_t)j * H * H;
  const float bias = biasall[j * H + d];

  __shared__ float hs[ROWS][H];
  __shared__ float srel[ROWS][R][H];
  __shared__ float sinv[ROWS][R];

  #pragma unroll
  for (int r = 0; r < ROWS; ++r) {
    int n = row0 + r;
    hs[r][d] = (n < N_all) ? h[(size_t)n * H + d] : 0.f;
  }

  const bool anyAgg = (row0 < NSRC);  // NSRC % ROWS == 0, no straddling blocks
  if (anyAgg) {
    for (int r = 0; r < ROWS; ++r) {
      int n = row0 + r;
      const int segb = (j * R) * NSRC + n;
      for (int rel = 0; rel < R; ++rel) {
        int beg = offs[segb + rel * NSRC];
        int end = offs[segb + rel * NSRC + 1];
        int cn = end - beg;
        float s = 0.f;
        int e = beg;
        for (; e + 4 <= end; e += 4) {
          int i0 = elist[e], i1 = elist[e + 1], i2 = elist[e + 2], i3 = elist[e + 3];
          float a0 = hsrc[(size_t)i0 * H + d];
          float a1 = hsrc[(size_t)i1 * H + d];
          float a2 = hsrc[(size_t)i2 * H + d];
          float a3 = hsrc[(size_t)i3 * H + d];
          s += (a0 + a1) + (a2 + a3);
        }
        for (; e < end; ++e) s += hsrc[(size_t)elist[e] * H + d];
        srel[r][rel][d] = s;
        if (d == 0) sinv[r][rel] = (cn > 0) ? 1.f / (float)cn : 0.f;
      }
    }
  }
  __syncthreads();

  float acc[ROWS];
  #pragma unroll
  for (int r = 0; r < ROWS; ++r) acc[r] = bias;

  // root matmul: thread d computes column d for all ROWS rows
  for (int k = 0; k < H; ++k) {
    float rk = root[k * H + d];
    #pragma unroll
    for (int r = 0; r < ROWS; ++r) acc[r] = fmaf(hs[r][k], rk, acc[r]);
  }

  if (anyAgg) {
    for (int rel = 0; rel < R; ++rel) {
      const float* Wr = W + ((size_t)(rel * B + b) * C) * C + dd;
      float t[ROWS];
      #pragma unroll
      for (int r = 0; r < ROWS; ++r) t[r] = 0.f;
      for (int c = 0; c < C; ++c) {
        float w = Wr[(size_t)c * C];
        #pragma unroll
        for (int r = 0; r < ROWS; ++r) t[r] = fmaf(srel[r][rel][b * C + c], w, t[r]);
      }
      #pragma unroll
      for (int r = 0; r < ROWS; ++r) acc[r] = fmaf(t[r], sinv[r][rel], acc[r]);
    }
  }

  #pragma unroll
  for (int r = 0; r < ROWS; ++r) {
    int n = row0 + r;
    if (n < N_all) out[((size_t)j * N_all + n) * H + d] = fmaxf(acc[r], 0.f);
  }
}

// ---------------- launch ----------------

extern "C" void kernel_launch(void* const* d_in, const int* in_sizes, int n_in,
                              void* d_out, int out_size, void* d_ws, size_t ws_size,
                              hipStream_t stream) {
  const float* x    = (const float*)d_in[0];
  const int*   ei   = (const int*)d_in[1];
  const int*   attr = (const int*)d_in[2];
  const float* emb  = (const float*)d_in[3];
  const float* cw   = (const float*)d_in[4];
  const float* cr   = (const float*)d_in[5];
  const float* cb   = (const float*)d_in[6];
  float* out = (float*)d_out;

  const int N = in_sizes[0] / F;   // 20000
  const int E = in_sizes[1] / 2;   // 640000
  const int NSEG = D * R * N;      // 480000

  char* ws = (char*)d_ws;
  size_t woff = 0;
  auto alloc = [&](size_t bytes) -> void* {
    void* p = ws + woff;
    woff = (woff + bytes + 255) & ~(size_t)255;
    return p;
  };
  float* h0     = (float*)alloc((size_t)N * H * 4);
  float* h1     = (float*)alloc((size_t)D * N * H * 4);
  int*   cnt    = (int*)alloc((size_t)NSEG * 4);
  int*   cexcl  = (int*)alloc((size_t)NSEG * 4);
  int*   bsum   = (int*)alloc(4096);
  int*   offs   = (int*)alloc((size_t)(NSEG + 1) * 4);
  int*   cursor = (int*)alloc((size_t)NSEG * 4);
  int*   elist  = (int*)alloc((size_t)D * E * 4);

  hipMemsetAsync(cnt, 0, (size_t)NSEG * 4, stream);
  count_edges<<<(E + 255) / 256, 256, 0, stream>>>(ei, attr, cnt, E, N);

  int nch = (NSEG + SCAN_CHUNK - 1) / SCAN_CHUNK;  // 938 <= 1024
  scan_a<<<nch, SCAN_CHUNK, 0, stream>>>(cnt, cexcl, bsum, NSEG);
  scan_b<<<1, 1024, 0, stream>>>(bsum, nch);
  scan_c<<<(NSEG + 255) / 256, 256, 0, stream>>>(cexcl, bsum, offs, NSEG, D * E);
  copy_int<<<(NSEG + 255) / 256, 256, 0, stream>>>(offs, cursor, NSEG);
  fill_edges<<<(E + 255) / 256, 256, 0, stream>>>(ei, attr, cursor, elist, E, N);

  gemm_h0<<<N / ROWS, 128, 0, stream>>>(x, emb, h0, N);

  // layer 0: h0 (N rows) -> h1 (3N rows)
  {
    dim3 grid(N / ROWS, D);
    conv_kernel<<<grid, 128, 0, stream>>>(h0, h0, offs, elist,
                                          cw, cr, cb, h1, N, N);
  }
  // layer 1: h1 (3N rows) -> out (9N rows); messages gather only rows < N of h1
  {
    dim3 grid((D * N) / ROWS, D);
    conv_kernel<<<grid, 128, 0, stream>>>(h1, h1, offs, elist,
                                          cw + (size_t)D * R * B * C * C,
                                          cr + (size_t)D * H * H,
                                          cb + (size_t)D * H,
                                          out, D * N, N);
  }
}

// Round 2
// 862.129 us; speedup vs baseline: 1.9076x; 1.9076x over previous
//
#include <hip/hip_runtime.h>

// RGCN encoder: N=20000 nodes, E=640000 edges, F=64, H=128, L=2 layers,
// D=3 edge-attr dims, R=8 relations, block-diag B=4 blocks of c=32.
// h grows by concat: 20000 -> 60000 -> 180000 rows.
//
// Structure (R2): per-dst CSR with packed (src,rel0,rel1,rel2) entries; one
// gather of h[src] serves all 3 edge-attr dims. LDS accumulation s[3][8][128]
// with lane-owned channel slices (no atomics). Block-diag W applied per row.
// Dense root GEMM + msg add + relu in a separate high-occupancy kernel.

constexpr int H  = 128;
constexpr int F  = 64;
constexpr int D  = 3;
constexpr int R  = 8;
constexpr int B  = 4;
constexpr int C  = 32;
constexpr int ROWS = 8;     // gemm_h0
constexpr int ROWSB = 16;   // matB
constexpr int SCAN_CHUNK = 512;

// ---------------- CSR build (per-dst) ----------------

__global__ void count_edges(const int* __restrict__ ei, const int* __restrict__ attr,
                            int* __restrict__ indeg, int* __restrict__ cnt8, int E) {
  int e = blockIdx.x * 256 + threadIdx.x;
  if (e >= E) return;
  int dst = ei[E + e];
  atomicAdd(&indeg[dst], 1);
  #pragma unroll
  for (int j = 0; j < D; ++j) {
    int r = attr[e * D + j];
    atomicAdd(&cnt8[dst * (D * R) + j * R + r], 1);
  }
}

__global__ void scan_a(const int* __restrict__ cnt, int* __restrict__ cexcl,
                       int* __restrict__ bsum, int nseg) {
  __shared__ int tmp[2][SCAN_CHUNK];
  int t = threadIdx.x;
  int gid = blockIdx.x * SCAN_CHUNK + t;
  int v = (gid < nseg) ? cnt[gid] : 0;
  int pa = 0;
  tmp[0][t] = v;
  __syncthreads();
  for (int off = 1; off < SCAN_CHUNK; off <<= 1) {
    tmp[1 - pa][t] = tmp[pa][t] + ((t >= off) ? tmp[pa][t - off] : 0);
    pa = 1 - pa;
    __syncthreads();
  }
  int incl = tmp[pa][t];
  if (gid < nseg) cexcl[gid] = incl - v;
  if (t == SCAN_CHUNK - 1) bsum[blockIdx.x] = incl;
}

__global__ void scan_b(int* __restrict__ bsum, int nblk) {
  __shared__ int tmp[2][1024];
  int t = threadIdx.x;
  int v = (t < nblk) ? bsum[t] : 0;
  int pa = 0;
  tmp[0][t] = v;
  __syncthreads();
  for (int off = 1; off < 1024; off <<= 1) {
    tmp[1 - pa][t] = tmp[pa][t] + ((t >= off) ? tmp[pa][t - off] : 0);
    pa = 1 - pa;
    __syncthreads();
  }
  if (t < nblk) bsum[t] = tmp[pa][t] - v;  // exclusive
}

__global__ void scan_c(const int* __restrict__ cexcl, const int* __restrict__ bsum,
                       int* __restrict__ offs, int nseg, int total) {
  int gid = blockIdx.x * 256 + threadIdx.x;
  if (gid < nseg) offs[gid] = cexcl[gid] + bsum[gid / SCAN_CHUNK];
  if (gid == 0) offs[nseg] = total;
}

__global__ void copy_int(const int* __restrict__ a, int* __restrict__ b, int n) {
  int i = blockIdx.x * 256 + threadIdx.x;
  if (i < n) b[i] = a[i];
}

__global__ void fill_edges(const int* __restrict__ ei, const int* __restrict__ attr,
                           int* __restrict__ cursor, unsigned* __restrict__ elist, int E) {
  int e = blockIdx.x * 256 + threadIdx.x;
  if (e >= E) return;
  int src = ei[e];
  int dst = ei[E + e];
  unsigned r0 = attr[e * D + 0], r1 = attr[e * D + 1], r2 = attr[e * D + 2];
  unsigned u = (unsigned)src | (r0 << 16) | (r1 << 20) | (r2 << 24);
  int p = atomicAdd(&cursor[dst], 1);
  elist[p] = u;
}

// ---------------- h0 = x @ emb ----------------

__global__ __launch_bounds__(128) void gemm_h0(const float* __restrict__ x,
                                               const float* __restrict__ emb,
                                               float* __restrict__ h0, int N) {
  __shared__ float xs[ROWS][F];
  int r0 = blockIdx.x * ROWS;
  for (int i = threadIdx.x; i < ROWS * F; i += 128)
    xs[i >> 6][i & 63] = x[(size_t)r0 * F + i];
  __syncthreads();
  int d = threadIdx.x;
  float acc[ROWS] = {};
  for (int k = 0; k < F; ++k) {
    float ev = emb[k * H + d];
    #pragma unroll
    for (int r = 0; r < ROWS; ++r) acc[r] = fmaf(xs[r][k], ev, acc[r]);
  }
  #pragma unroll
  for (int r = 0; r < ROWS; ++r) h0[(size_t)(r0 + r) * H + d] = acc[r];
}

// ---------------- aggregation + block-diag transform ----------------
// For dst node n: m[j][n][d] = sum_r sinv(j,r) * (W_{j,r} @ s_{j,r})[d]
// where s_{j,r} = sum of raw hsrc rows over edges with attr[:,j]==r.

__global__ __launch_bounds__(128) void agg_kernel(
    const float* __restrict__ hsrc, const int* __restrict__ offs,
    const unsigned* __restrict__ elist, const int* __restrict__ cnt8,
    const float* __restrict__ Wall, float* __restrict__ m, int N) {
  const int n = blockIdx.x;
  const int d = threadIdx.x;
  __shared__ float s[D][R][H];   // 12 KB
  __shared__ float sinv[D * R];

  #pragma unroll
  for (int j = 0; j < D; ++j)
    #pragma unroll
    for (int r = 0; r < R; ++r) s[j][r][d] = 0.f;
  if (d < D * R) {
    int c = cnt8[n * (D * R) + d];
    sinv[d] = (c > 0) ? 1.f / (float)c : 0.f;
  }

  const int beg = offs[n], end = offs[n + 1];
  // 2-deep pipeline: prefetch next entry + gather while doing LDS adds.
  unsigned u = 0; float v = 0.f;
  if (beg < end) {
    u = elist[beg];
    v = hsrc[(size_t)(u & 0xFFFFu) * H + d];
  }
  for (int e = beg; e < end;) {
    unsigned uc = u; float vc = v;
    ++e;
    if (e < end) {
      u = elist[e];
      v = hsrc[(size_t)(u & 0xFFFFu) * H + d];
    }
    s[0][(uc >> 16) & 7][d] += vc;
    s[1][(uc >> 20) & 7][d] += vc;
    s[2][(uc >> 24) & 7][d] += vc;
  }
  __syncthreads();

  const int b = d >> 5, dd = d & 31;
  #pragma unroll
  for (int j = 0; j < D; ++j) {
    float acc = 0.f;
    for (int r = 0; r < R; ++r) {
      const float* Wr = Wall + (((size_t)(j * R + r) * B + b) * C) * C + dd;
      float t = 0.f;
      #pragma unroll
      for (int c = 0; c < C; ++c) t = fmaf(s[j][r][b * C + c], Wr[(size_t)c * C], t);
      acc = fmaf(t, sinv[j * R + r], acc);
    }
    m[((size_t)j * N + n) * H + d] = acc;
  }
}

// ---------------- dense root matmul + msg add + relu ----------------
// out[j*N_all + n] = relu( h[n] @ root_j + bias_j + (n < N ? m[j][n] : 0) )

__global__ __launch_bounds__(128) void matB(
    const float* __restrict__ h, const float* __restrict__ m,
    const float* __restrict__ rootall, const float* __restrict__ biasall,
    float* __restrict__ out, int N_all, int N) {
  const int j = blockIdx.y;
  const int row0 = blockIdx.x * ROWSB;
  const int d = threadIdx.x;
  const float* root = rootall + (size_t)j * H * H;
  __shared__ float hs[ROWSB][H];

  #pragma unroll
  for (int r = 0; r < ROWSB; ++r)
    hs[r][d] = h[(size_t)(row0 + r) * H + d];
  __syncthreads();

  const float bias = biasall[j * H + d];
  float acc[ROWSB];
  #pragma unroll
  for (int r = 0; r < ROWSB; ++r) acc[r] = bias;

  for (int k = 0; k < H; ++k) {
    float rk = root[(size_t)k * H + d];
    #pragma unroll
    for (int r = 0; r < ROWSB; ++r) acc[r] = fmaf(hs[r][k], rk, acc[r]);
  }

  if (row0 + ROWSB <= N) {
    #pragma unroll
    for (int r = 0; r < ROWSB; ++r)
      acc[r] += m[((size_t)j * N + row0 + r) * H + d];
  }

  #pragma unroll
  for (int r = 0; r < ROWSB; ++r)
    out[((size_t)j * N_all + row0 + r) * H + d] = fmaxf(acc[r], 0.f);
}

// ---------------- launch ----------------

extern "C" void kernel_launch(void* const* d_in, const int* in_sizes, int n_in,
                              void* d_out, int out_size, void* d_ws, size_t ws_size,
                              hipStream_t stream) {
  const float* x    = (const float*)d_in[0];
  const int*   ei   = (const int*)d_in[1];
  const int*   attr = (const int*)d_in[2];
  const float* emb  = (const float*)d_in[3];
  const float* cw   = (const float*)d_in[4];
  const float* cr   = (const float*)d_in[5];
  const float* cb   = (const float*)d_in[6];
  float* out = (float*)d_out;

  const int N = in_sizes[0] / F;   // 20000
  const int E = in_sizes[1] / 2;   // 640000

  char* ws = (char*)d_ws;
  size_t woff = 0;
  auto alloc = [&](size_t bytes) -> void* {
    void* p = ws + woff;
    woff = (woff + bytes + 255) & ~(size_t)255;
    return p;
  };
  float*    h0     = (float*)alloc((size_t)N * H * 4);
  float*    h1     = (float*)alloc((size_t)D * N * H * 4);
  float*    m      = (float*)alloc((size_t)D * N * H * 4);
  int*      indeg  = (int*)alloc((size_t)N * 4);
  int*      cnt8   = (int*)alloc((size_t)N * D * R * 4);
  int*      cexcl  = (int*)alloc((size_t)N * 4);
  int*      bsum   = (int*)alloc(4096);
  int*      offs   = (int*)alloc((size_t)(N + 1) * 4);
  int*      cursor = (int*)alloc((size_t)N * 4);
  unsigned* elist  = (unsigned*)alloc((size_t)E * 4);

  // counts
  hipMemsetAsync(indeg, 0, (size_t)N * 4, stream);
  hipMemsetAsync(cnt8, 0, (size_t)N * D * R * 4, stream);
  count_edges<<<(E + 255) / 256, 256, 0, stream>>>(ei, attr, indeg, cnt8, E);

  // scan indeg -> offs
  int nch = (N + SCAN_CHUNK - 1) / SCAN_CHUNK;  // 40
  scan_a<<<nch, SCAN_CHUNK, 0, stream>>>(indeg, cexcl, bsum, N);
  scan_b<<<1, 1024, 0, stream>>>(bsum, nch);
  scan_c<<<(N + 255) / 256, 256, 0, stream>>>(cexcl, bsum, offs, N, E);
  copy_int<<<(N + 255) / 256, 256, 0, stream>>>(offs, cursor, N);
  fill_edges<<<(E + 255) / 256, 256, 0, stream>>>(ei, attr, cursor, elist, E);

  // h0 = x @ emb
  gemm_h0<<<N / ROWS, 128, 0, stream>>>(x, emb, h0, N);

  // layer 0
  agg_kernel<<<N, 128, 0, stream>>>(h0, offs, elist, cnt8, cw, m, N);
  {
    dim3 grid(N / ROWSB, D);
    matB<<<grid, 128, 0, stream>>>(h0, m, cr, cb, h1, N, N);
  }
  // layer 1 (gathers only rows < N of h1)
  agg_kernel<<<N, 128, 0, stream>>>(h1, offs, elist, cnt8,
                                    cw + (size_t)D * R * B * C * C, m, N);
  {
    dim3 grid((D * N) / ROWSB, D);
    matB<<<grid, 128, 0, stream>>>(h1, m,
                                   cr + (size_t)D * H * H,
                                   cb + (size_t)D * H,
                                   out, D * N, N);
  }
}